// Round 2
// baseline (233.285 us; speedup 1.0000x reference)
//
#include <hip/hip_runtime.h>

// yoloLoss on MI355X — R2: no-LDS direct-load variant.
// Key trick: a pair of adjacent cells = 60 floats = 240 B = 15 float4,
// and 240 % 16 == 0, so per-thread float4 loads are always 16B-aligned.
// One thread per cell pair; no staging transpose, no barriers, one kernel.
// pred/target: (4096,14,14,30) fp32 = 96.3 MB each. HBM floor ~31 us.

#define FEAT 30
#define CELLS 802816            // 4096*14*14
#define PAIRS (CELLS / 2)       // 401408
#define TPB 256
#define NB (PAIRS / TPB)        // 1568 exactly

__device__ __forceinline__ float iou_f(float x1, float y1, float w1, float h1,
                                       float x2, float y2, float w2, float h2) {
    float b1x1 = x1 - 0.5f * w1, b1x2 = x1 + 0.5f * w1;
    float b1y1 = y1 - 0.5f * h1, b1y2 = y1 + 0.5f * h1;
    float b2x1 = x2 - 0.5f * w2, b2x2 = x2 + 0.5f * w2;
    float b2y1 = y2 - 0.5f * h2, b2y2 = y2 + 0.5f * h2;
    float iw = fmaxf(fminf(b1x2, b2x2) - fmaxf(b1x1, b2x1), 0.0f);
    float ih = fmaxf(fminf(b1y2, b2y2) - fmaxf(b1y1, b2y1), 0.0f);
    float inter = iw * ih;
    float a1 = (b1x2 - b1x1) * (b1y2 - b1y1);
    float a2 = (b2x2 - b2x1) * (b2y2 - b2y1);
    return inter / (a1 + a2 - inter + 1e-6f);
}

// Per-cell YOLO loss; p/t point at 30 consecutive register-resident floats.
// All indices compile-time constants after inlining -> stays in VGPRs.
__device__ __forceinline__ float cell_loss(const float* p, const float* t) {
    const bool obj0 = t[4] > 0.0f;
    const bool obj1 = t[9] > 0.0f;
    const float mf = obj0 ? 1.0f : 0.0f;

    float d0 = p[4] - t[4];
    float d1 = p[9] - t[9];
    float noobj = (obj0 ? 0.0f : d0 * d0) + (obj1 ? 0.0f : d1 * d1);

    float iou0 = iou_f(p[0], p[1], p[2], p[3], t[0], t[1], t[2], t[3]);
    float iou1 = iou_f(p[5], p[6], p[7], p[8], t[5], t[6], t[7], t[8]);
    const bool sel1 = iou1 > iou0;   // argmax tie -> box 0

    float pbx = sel1 ? p[5] : p[0];
    float pby = sel1 ? p[6] : p[1];
    float pbw = sel1 ? p[7] : p[2];
    float pbh = sel1 ? p[8] : p[3];
    float pbc = sel1 ? p[9] : p[4];
    float tbx = sel1 ? t[5] : t[0];
    float tby = sel1 ? t[6] : t[1];
    float tbw = sel1 ? t[7] : t[2];
    float tbh = sel1 ? t[8] : t[3];
    float tbc = sel1 ? t[9] : t[4];

    float dx = pbx - tbx, dy = pby - tby;
    float xy = dx * dx + dy * dy;

    float pw = sqrtf(fabsf(pbw) + 1e-6f);
    float ph = sqrtf(fabsf(pbh) + 1e-6f);
    float tw = sqrtf(obj0 ? tbw : 1.0f);   // t_wh_safe
    float th = sqrtf(obj0 ? tbh : 1.0f);
    float dw = pw - tw, dh = ph - th;
    float wh = dw * dw + dh * dh;

    float dc = pbc - tbc;
    float obj_l = dc * dc;

    // nonbest conf: LAMBDA_NOOBJ applied inside noobj AND again in total
    float nonbest = (p[4] + p[9]) - pbc;
    noobj += 0.5f * mf * nonbest * nonbest;

    float cls = 0.0f;
#pragma unroll
    for (int k = 10; k < FEAT; ++k) {
        float d = p[k] - t[k];
        cls += d * d;
    }

    return 5.0f * mf * (xy + wh) + mf * obj_l + 0.5f * noobj + mf * cls;
}

__global__ __launch_bounds__(TPB) void yolo_kernel(
        const float* __restrict__ pred, const float* __restrict__ tgt,
        float* __restrict__ out) {
    __shared__ float wave_sum[TPB / 64];

    const int tid = threadIdx.x;
    const long long pair = (long long)blockIdx.x * TPB + tid;

    // 15 aligned float4 per array covering two adjacent cells (240 B).
    const float4* gp = (const float4*)(pred + pair * (2 * FEAT));
    const float4* gt = (const float4*)(tgt + pair * (2 * FEAT));

    float pf[2 * FEAT], tf[2 * FEAT];
#pragma unroll
    for (int i = 0; i < 15; ++i) {
        float4 a = gp[i];
        pf[4 * i] = a.x; pf[4 * i + 1] = a.y; pf[4 * i + 2] = a.z; pf[4 * i + 3] = a.w;
        float4 b = gt[i];
        tf[4 * i] = b.x; tf[4 * i + 1] = b.y; tf[4 * i + 2] = b.z; tf[4 * i + 3] = b.w;
    }

    float v = cell_loss(pf, tf) + cell_loss(pf + FEAT, tf + FEAT);

    // wave shuffle reduce, then cross-wave via LDS, one atomic per block
#pragma unroll
    for (int off = 32; off > 0; off >>= 1) v += __shfl_down(v, off, 64);
    if ((tid & 63) == 0) wave_sum[tid >> 6] = v;
    __syncthreads();
    if (tid == 0) {
        float blk = wave_sum[0] + wave_sum[1] + wave_sum[2] + wave_sum[3];
        atomicAdd(out, blk * (1.0f / 4096.0f));
    }
}

extern "C" void kernel_launch(void* const* d_in, const int* in_sizes, int n_in,
                              void* d_out, int out_size, void* d_ws, size_t ws_size,
                              hipStream_t stream) {
    const float* pred = (const float*)d_in[0];
    const float* tgt  = (const float*)d_in[1];
    float* out = (float*)d_out;

    // d_out is re-poisoned to 0xAA before every launch -> zero it first.
    // hipMemsetAsync on the stream is graph-capturable (memset node).
    hipMemsetAsync(out, 0, sizeof(float), stream);
    yolo_kernel<<<NB, TPB, 0, stream>>>(pred, tgt, out);
}

// Round 3
// 215.166 us; speedup vs baseline: 1.0842x; 1.0842x over previous
//
#include <hip/hip_runtime.h>

// yoloLoss on MI355X — R3: wave-synchronous global_load_lds streaming.
// 1 wave/block, double-buffered LDS tiles, no s_barrier anywhere.
// Tile = 64 cells = 7680 B per array; staged as 15 global_load_lds_dwordx4:
//   7 pred-full + 1 mixed (lanes 0-31 pred tail, 32-63 tgt head) + 7 tgt-full.
// pred/target: (4096,14,14,30) fp32 = 96.3 MB each. HBM floor ~31 us.

#define FEAT 30
#define CELLS 802816                 // 4096*14*14
#define TILE_CELLS 64
#define TILE_FLOATS (TILE_CELLS * FEAT)   // 1920 floats = 7680 B per array
#define BUF_FLOATS (2 * TILE_FLOATS)      // pred+tgt per buffer = 3840 floats
#define TILES_PER_BLOCK 8
#define NB (CELLS / (TILE_CELLS * TILES_PER_BLOCK))  // 1568 exactly

__device__ __forceinline__ void load16(const float* g, float* l) {
    __builtin_amdgcn_global_load_lds(
        (const __attribute__((address_space(1))) void*)g,
        (__attribute__((address_space(3))) void*)l, 16, 0, 0);
}

__device__ __forceinline__ float iou_f(float x1, float y1, float w1, float h1,
                                       float x2, float y2, float w2, float h2) {
    float b1x1 = x1 - 0.5f * w1, b1x2 = x1 + 0.5f * w1;
    float b1y1 = y1 - 0.5f * h1, b1y2 = y1 + 0.5f * h1;
    float b2x1 = x2 - 0.5f * w2, b2x2 = x2 + 0.5f * w2;
    float b2y1 = y2 - 0.5f * h2, b2y2 = y2 + 0.5f * h2;
    float iw = fmaxf(fminf(b1x2, b2x2) - fmaxf(b1x1, b2x1), 0.0f);
    float ih = fmaxf(fminf(b1y2, b2y2) - fmaxf(b1y1, b2y1), 0.0f);
    float inter = iw * ih;
    float a1 = (b1x2 - b1x1) * (b1y2 - b1y1);
    float a2 = (b2x2 - b2x1) * (b2y2 - b2y1);
    return inter / (a1 + a2 - inter + 1e-6f);
}

// Verified absmax==0 in R1/R2. p/t are 30 register-resident floats.
__device__ __forceinline__ float cell_loss(const float* p, const float* t) {
    const bool obj0 = t[4] > 0.0f;
    const bool obj1 = t[9] > 0.0f;
    const float mf = obj0 ? 1.0f : 0.0f;

    float d0 = p[4] - t[4];
    float d1 = p[9] - t[9];
    float noobj = (obj0 ? 0.0f : d0 * d0) + (obj1 ? 0.0f : d1 * d1);

    float iou0 = iou_f(p[0], p[1], p[2], p[3], t[0], t[1], t[2], t[3]);
    float iou1 = iou_f(p[5], p[6], p[7], p[8], t[5], t[6], t[7], t[8]);
    const bool sel1 = iou1 > iou0;   // argmax tie -> box 0

    float pbx = sel1 ? p[5] : p[0];
    float pby = sel1 ? p[6] : p[1];
    float pbw = sel1 ? p[7] : p[2];
    float pbh = sel1 ? p[8] : p[3];
    float pbc = sel1 ? p[9] : p[4];
    float tbx = sel1 ? t[5] : t[0];
    float tby = sel1 ? t[6] : t[1];
    float tbw = sel1 ? t[7] : t[2];
    float tbh = sel1 ? t[8] : t[3];
    float tbc = sel1 ? t[9] : t[4];

    float dx = pbx - tbx, dy = pby - tby;
    float xy = dx * dx + dy * dy;

    float pw = sqrtf(fabsf(pbw) + 1e-6f);
    float ph = sqrtf(fabsf(pbh) + 1e-6f);
    float tw = sqrtf(obj0 ? tbw : 1.0f);   // t_wh_safe
    float th = sqrtf(obj0 ? tbh : 1.0f);
    float dw = pw - tw, dh = ph - th;
    float wh = dw * dw + dh * dh;

    float dc = pbc - tbc;
    float obj_l = dc * dc;

    float nonbest = (p[4] + p[9]) - pbc;   // LAMBDA_NOOBJ applied twice (ref)
    noobj += 0.5f * mf * nonbest * nonbest;

    float cls = 0.0f;
#pragma unroll
    for (int k = 10; k < FEAT; ++k) {
        float d = p[k] - t[k];
        cls += d * d;
    }

    return 5.0f * mf * (xy + wh) + mf * obj_l + 0.5f * noobj + mf * cls;
}

__global__ __launch_bounds__(64, 2) void yolo_kernel(
        const float* __restrict__ pred, const float* __restrict__ tgt,
        float* __restrict__ out) {
    // 30 KB LDS -> 5 blocks(waves)/CU. Layout per buffer (floats):
    //   [0,1920)  predLDS   [1920,3840) tgtLDS
    __shared__ float lds[2 * BUF_FLOATS];

    const int lane = threadIdx.x;
    const float* predT = pred + (long long)blockIdx.x * TILES_PER_BLOCK * TILE_FLOATS;
    const float* tgtT  = tgt  + (long long)blockIdx.x * TILES_PER_BLOCK * TILE_FLOATS;

    // Per-lane global source pointers (floats; lane*4 floats = lane*16 B):
    const float* pl = predT + lane * 4;                 // pred bytes 0..7167 (+j*1024)
    const float* ml = (lane < 32) ? (predT + 1792 + lane * 4)   // pred tail 7168..7679
                                  : (tgtT - 128 + lane * 4);    // tgt head 0..511
    const float* tl = tgtT + 128 + lane * 4;            // tgt bytes 512..7679 (+j*1024)

    // Stage one tile (15 x global_load_lds_dwordx4), wave-uniform LDS bases.
    auto stage = [&](int buf, int tileFloatOff) {
        float* L = lds + buf * BUF_FLOATS;
        const float* p = pl + tileFloatOff;
        const float* m = ml + tileFloatOff;
        const float* t = tl + tileFloatOff;
#pragma unroll
        for (int j = 0; j < 7; ++j) load16(p + j * 256, L + j * 256);
        load16(m, L + 1792);
#pragma unroll
        for (int j = 0; j < 7; ++j) load16(t + j * 256, L + 2048 + j * 256);
    };

    stage(0, 0);
    float acc = 0.0f;

#pragma unroll 1
    for (int i = 0; i < TILES_PER_BLOCK; ++i) {
        if (i + 1 < TILES_PER_BLOCK) stage((i + 1) & 1, (i + 1) * TILE_FLOATS);

        // LDS -> registers (float2, 8B-aligned: cell stride 120 B).
        const float2* pc = (const float2*)(lds + (i & 1) * BUF_FLOATS + lane * FEAT);
        const float2* tc = (const float2*)(lds + (i & 1) * BUF_FLOATS + TILE_FLOATS + lane * FEAT);
        float pf[FEAT], tf[FEAT];
#pragma unroll
        for (int k = 0; k < FEAT / 2; ++k) {
            float2 a = pc[k]; pf[2 * k] = a.x; pf[2 * k + 1] = a.y;
            float2 b = tc[k]; tf[2 * k] = b.x; tf[2 * k + 1] = b.y;
        }
        acc += cell_loss(pf, tf);
    }

    // Wave-level reduce (single wave per block), one atomic per block.
    float v = acc;
#pragma unroll
    for (int off = 32; off > 0; off >>= 1) v += __shfl_down(v, off, 64);
    if (lane == 0) atomicAdd(out, v * (1.0f / 4096.0f));
}

extern "C" void kernel_launch(void* const* d_in, const int* in_sizes, int n_in,
                              void* d_out, int out_size, void* d_ws, size_t ws_size,
                              hipStream_t stream) {
    const float* pred = (const float*)d_in[0];
    const float* tgt  = (const float*)d_in[1];
    float* out = (float*)d_out;

    hipMemsetAsync(out, 0, sizeof(float), stream);  // d_out is poisoned 0xAA
    yolo_kernel<<<NB, 64, 0, stream>>>(pred, tgt, out);
}

// Round 4
// 212.894 us; speedup vs baseline: 1.0958x; 1.0107x over previous
//
#include <hip/hip_runtime.h>

// yoloLoss on MI355X — R4: one-shot single-wave blocks, 10 waves/CU.
// Each 64-thread block: 15 global_load_lds_dwordx4 -> vmcnt(0) (its own
// loads only) -> compute 64 cells -> 1 partial. No s_barrier, no double
// buffer; latency hidden by 10 independent resident waves per CU.
// pred/target: (4096,14,14,30) fp32 = 96.3 MB each. HBM floor ~31 us.

#define FEAT 30
#define CELLS 802816                    // 4096*14*14
#define TILE_CELLS 64
#define TILE_FLOATS (TILE_CELLS * FEAT) // 1920 floats = 7680 B per array
#define NB (CELLS / TILE_CELLS)         // 12544 blocks
#define RED_TPB 256

__device__ __forceinline__ void load16(const float* g, float* l) {
    __builtin_amdgcn_global_load_lds(
        (const __attribute__((address_space(1))) void*)g,
        (__attribute__((address_space(3))) void*)l, 16, 0, 0);
}

__device__ __forceinline__ float iou_f(float x1, float y1, float w1, float h1,
                                       float x2, float y2, float w2, float h2) {
    float b1x1 = x1 - 0.5f * w1, b1x2 = x1 + 0.5f * w1;
    float b1y1 = y1 - 0.5f * h1, b1y2 = y1 + 0.5f * h1;
    float b2x1 = x2 - 0.5f * w2, b2x2 = x2 + 0.5f * w2;
    float b2y1 = y2 - 0.5f * h2, b2y2 = y2 + 0.5f * h2;
    float iw = fmaxf(fminf(b1x2, b2x2) - fmaxf(b1x1, b2x1), 0.0f);
    float ih = fmaxf(fminf(b1y2, b2y2) - fmaxf(b1y1, b2y1), 0.0f);
    float inter = iw * ih;
    float a1 = (b1x2 - b1x1) * (b1y2 - b1y1);
    float a2 = (b2x2 - b2x1) * (b2y2 - b2y1);
    return inter / (a1 + a2 - inter + 1e-6f);
}

// Verified absmax==0 in R1-R3. p/t: 30 register-resident floats per cell.
__device__ __forceinline__ float cell_loss(const float* p, const float* t) {
    const bool obj0 = t[4] > 0.0f;
    const bool obj1 = t[9] > 0.0f;
    const float mf = obj0 ? 1.0f : 0.0f;

    float d0 = p[4] - t[4];
    float d1 = p[9] - t[9];
    float noobj = (obj0 ? 0.0f : d0 * d0) + (obj1 ? 0.0f : d1 * d1);

    float iou0 = iou_f(p[0], p[1], p[2], p[3], t[0], t[1], t[2], t[3]);
    float iou1 = iou_f(p[5], p[6], p[7], p[8], t[5], t[6], t[7], t[8]);
    const bool sel1 = iou1 > iou0;   // argmax tie -> box 0

    float pbx = sel1 ? p[5] : p[0];
    float pby = sel1 ? p[6] : p[1];
    float pbw = sel1 ? p[7] : p[2];
    float pbh = sel1 ? p[8] : p[3];
    float pbc = sel1 ? p[9] : p[4];
    float tbx = sel1 ? t[5] : t[0];
    float tby = sel1 ? t[6] : t[1];
    float tbw = sel1 ? t[7] : t[2];
    float tbh = sel1 ? t[8] : t[3];
    float tbc = sel1 ? t[9] : t[4];

    float dx = pbx - tbx, dy = pby - tby;
    float xy = dx * dx + dy * dy;

    float pw = sqrtf(fabsf(pbw) + 1e-6f);
    float ph = sqrtf(fabsf(pbh) + 1e-6f);
    float tw = sqrtf(obj0 ? tbw : 1.0f);   // t_wh_safe
    float th = sqrtf(obj0 ? tbh : 1.0f);
    float dw = pw - tw, dh = ph - th;
    float wh = dw * dw + dh * dh;

    float dc = pbc - tbc;
    float obj_l = dc * dc;

    float nonbest = (p[4] + p[9]) - pbc;   // LAMBDA_NOOBJ applied twice (ref)
    noobj += 0.5f * mf * nonbest * nonbest;

    float cls = 0.0f;
#pragma unroll
    for (int k = 10; k < FEAT; ++k) {
        float d = p[k] - t[k];
        cls += d * d;
    }

    return 5.0f * mf * (xy + wh) + mf * obj_l + 0.5f * noobj + mf * cls;
}

__global__ __launch_bounds__(64) void yolo_kernel(
        const float* __restrict__ pred, const float* __restrict__ tgt,
        float* __restrict__ partials) {
    // 15,360 B LDS -> 10 blocks/CU. Layout (floats): [0,1920) pred, [1920,3840) tgt
    __shared__ float lds[2 * TILE_FLOATS];

    const int lane = threadIdx.x;
    const float* predT = pred + (long long)blockIdx.x * TILE_FLOATS;
    const float* tgtT  = tgt  + (long long)blockIdx.x * TILE_FLOATS;

    // 15 x global_load_lds_dwordx4, LDS dest = uniform base + lane*16B:
    //  7 pred-full | 1 mixed (lanes 0-31: pred tail, 32-63: tgt head) | 7 tgt-full
    const float* pl = predT + lane * 4;
    const float* ml = (lane < 32) ? (predT + 1792 + lane * 4)
                                  : (tgtT - 128 + lane * 4);
    const float* tl = tgtT + 128 + lane * 4;
#pragma unroll
    for (int j = 0; j < 7; ++j) load16(pl + j * 256, lds + j * 256);
    load16(ml, lds + 1792);
#pragma unroll
    for (int j = 0; j < 7; ++j) load16(tl + j * 256, lds + 2048 + j * 256);

    // Compiler inserts s_waitcnt vmcnt(0) here — exactly this wave's 15 loads.
    __builtin_amdgcn_s_waitcnt(0x3f70);  // vmcnt(0), belt+braces

    // LDS -> registers (float2; cell stride 120 B, 8B-aligned)
    const float2* pc = (const float2*)(lds + lane * FEAT);
    const float2* tc = (const float2*)(lds + TILE_FLOATS + lane * FEAT);
    float pf[FEAT], tf[FEAT];
#pragma unroll
    for (int k = 0; k < FEAT / 2; ++k) {
        float2 a = pc[k]; pf[2 * k] = a.x; pf[2 * k + 1] = a.y;
        float2 b = tc[k]; tf[2 * k] = b.x; tf[2 * k + 1] = b.y;
    }

    float v = cell_loss(pf, tf);
#pragma unroll
    for (int off = 32; off > 0; off >>= 1) v += __shfl_down(v, off, 64);
    if (lane == 0) partials[blockIdx.x] = v;
}

__global__ __launch_bounds__(RED_TPB) void yolo_reduce_kernel(
        const float* __restrict__ partials, float* __restrict__ out) {
    __shared__ float wave_sum[RED_TPB / 64];
    const int tid = threadIdx.x;
    float v = 0.0f;
#pragma unroll 1
    for (int i = tid; i < NB; i += RED_TPB) v += partials[i];
#pragma unroll
    for (int off = 32; off > 0; off >>= 1) v += __shfl_down(v, off, 64);
    if ((tid & 63) == 0) wave_sum[tid >> 6] = v;
    __syncthreads();
    if (tid == 0)
        out[0] = (wave_sum[0] + wave_sum[1] + wave_sum[2] + wave_sum[3]) *
                 (1.0f / 4096.0f);
}

extern "C" void kernel_launch(void* const* d_in, const int* in_sizes, int n_in,
                              void* d_out, int out_size, void* d_ws, size_t ws_size,
                              hipStream_t stream) {
    const float* pred = (const float*)d_in[0];
    const float* tgt  = (const float*)d_in[1];
    float* out = (float*)d_out;
    float* partials = (float*)d_ws;   // 12544 floats = 50 KB << ws_size

    yolo_kernel<<<NB, 64, 0, stream>>>(pred, tgt, partials);
    yolo_reduce_kernel<<<1, RED_TPB, 0, stream>>>(partials, out);
}